// Round 1
// baseline (426.461 us; speedup 1.0000x reference)
//
#include <hip/hip_runtime.h>
#include <math.h>

// Problem constants
#define BB 2
#define HH 64
#define WW 64
#define DM 128
#define EE 256
#define NN 16
#define RR 8
#define HW (HH*WW)          // 4096
#define CH_TOT (2*RR + 2*NN) // 48

__device__ __forceinline__ float gelu_exact(float v) {
    return 0.5f * v * (1.f + erff(v * 0.70710678118654752440f));
}
__device__ __forceinline__ float softplus_f(float v) {
    return fmaxf(v, 0.f) + log1pf(__expf(-fabsf(v)));
}

// ---------------------------------------------------------------------------
// K1: per spatial row (b,i). Computes u = gelu(x@ipw^T + ipb), dbc = u@xpw^T+xpb,
// deltaT/deltaL = softplus(d{T,L}@dt{T,L}w^T + b). Writes transposed layouts:
//   u_t, dT_t, dL_t : [B,E,H,W];  Bm_t, Cm_t : [B,N,H,W]
// ---------------------------------------------------------------------------
__global__ __launch_bounds__(256) void k1_proj(
    const float* __restrict__ x,
    const float* __restrict__ ipw, const float* __restrict__ ipb,
    const float* __restrict__ xpw, const float* __restrict__ xpb,
    const float* __restrict__ dtTw, const float* __restrict__ dtTb,
    const float* __restrict__ dtLw, const float* __restrict__ dtLb,
    float* __restrict__ u_t, float* __restrict__ dT_t, float* __restrict__ dL_t,
    float* __restrict__ Bm_t, float* __restrict__ Cm_t)
{
    __shared__ float xs[64][129];   // x row tile, padded (bank-safe)
    __shared__ float us[64][65];    // u chunk (64 e x 64 j)
    __shared__ float dbcs[48][65];  // dbc tile

    const int row = blockIdx.x;          // b*64 + i
    const int b = row >> 6, i = row & 63;
    const int t = threadIdx.x;
    const int w = t >> 6, j = t & 63;    // wave id, lane (= column j)

    const float* xrow = x + (size_t)row * (WW * DM);
    for (int idx = t; idx < WW * DM; idx += 256) {
        xs[idx >> 7][idx & 127] = xrow[idx];
    }
    __syncthreads();

    float accD[12];
    #pragma unroll
    for (int cc = 0; cc < 12; ++cc) accD[cc] = 0.f;

    for (int ch = 0; ch < 4; ++ch) {
        // u for e = ch*64 + w*16 + ee
        const int e0 = ch * 64 + w * 16;
        float acc[16];
        #pragma unroll
        for (int ee = 0; ee < 16; ++ee) acc[ee] = 0.f;
        for (int k = 0; k < DM; ++k) {
            float xv = xs[j][k];
            #pragma unroll
            for (int ee = 0; ee < 16; ++ee)
                acc[ee] = fmaf(xv, ipw[(e0 + ee) * DM + k], acc[ee]);
        }
        #pragma unroll
        for (int ee = 0; ee < 16; ++ee) {
            const int e = e0 + ee;
            float g = gelu_exact(acc[ee] + ipb[e]);
            us[w * 16 + ee][j] = g;
            u_t[(((size_t)(b * EE + e) * HH + i) << 6) + j] = g;
        }
        __syncthreads();
        // dbc accumulation over this e-chunk; wave w owns c = w*12 .. w*12+11
        for (int e64 = 0; e64 < 64; ++e64) {
            float uv = us[e64][j];
            const int e = ch * 64 + e64;
            #pragma unroll
            for (int cc = 0; cc < 12; ++cc)
                accD[cc] = fmaf(xpw[(w * 12 + cc) * EE + e], uv, accD[cc]);
        }
        __syncthreads();
    }

    #pragma unroll
    for (int cc = 0; cc < 12; ++cc) {
        const int c = w * 12 + cc;
        dbcs[c][j] = accD[cc] + xpb[c];
    }
    __syncthreads();

    // Bm, Cm (with bias already added)
    for (int n = w; n < NN; n += 4) {
        Bm_t[(((size_t)(b * NN + n) * HH + i) << 6) + j] = dbcs[2 * RR + n][j];
        Cm_t[(((size_t)(b * NN + n) * HH + i) << 6) + j] = dbcs[2 * RR + NN + n][j];
    }

    // deltaT / deltaL ; wave w owns e = w*64 .. w*64+63
    float dtv[8], dlv[8];
    #pragma unroll
    for (int r = 0; r < 8; ++r) { dtv[r] = dbcs[r][j]; dlv[r] = dbcs[RR + r][j]; }
    for (int ee = 0; ee < 64; ++ee) {
        const int e = w * 64 + ee;
        float sT = dtTb[e], sL = dtLb[e];
        #pragma unroll
        for (int r = 0; r < 8; ++r) {
            sT = fmaf(dtv[r], dtTw[e * RR + r], sT);
            sL = fmaf(dlv[r], dtLw[e * RR + r], sL);
        }
        dT_t[(((size_t)(b * EE + e) * HH + i) << 6) + j] = softplus_f(sT);
        dL_t[(((size_t)(b * EE + e) * HH + i) << 6) + j] = softplus_f(sL);
    }
}

// ---------------------------------------------------------------------------
// K2: wavefront scan. Block per (b,e): 16 waves, wave n handles state n,
// lane j = column. Rows sequential; per-row 64-lane Hillis-Steele scan of
// (a,b) with combine (a1,b1)+(a2,b2) -> (a1*a2, a2*b1+b2).
// Writes ys_t[B,E,H,W] = gelu(sum_n h*Cm + u*D).
// ---------------------------------------------------------------------------
__global__ __launch_bounds__(1024) void k2_scan(
    const float* __restrict__ u_t, const float* __restrict__ dT_t,
    const float* __restrict__ dL_t, const float* __restrict__ Bm_t,
    const float* __restrict__ Cm_t, const float* __restrict__ ATl,
    const float* __restrict__ ALl, const float* __restrict__ Dp,
    float* __restrict__ ys_t)
{
    __shared__ float contrib[NN][65];

    const int be = blockIdx.x;           // b*256 + e
    const int b = be >> 8, e = be & 255;
    const int t = threadIdx.x;
    const int n = t >> 6, j = t & 63;

    const float AT = -__expf(ATl[e * NN + n]);
    const float AL = -__expf(ALl[e * NN + n]);
    const float De = Dp[e];

    const float* dTp = dT_t + ((size_t)be << 12);
    const float* dLp = dL_t + ((size_t)be << 12);
    const float* up  = u_t  + ((size_t)be << 12);
    const float* bmp = Bm_t + ((size_t)(b * NN + n) << 12);
    const float* cmp = Cm_t + ((size_t)(b * NN + n) << 12);
    float* ysp = ys_t + ((size_t)be << 12);

    float h = 0.f;
    for (int i = 0; i < HH; ++i) {
        const int off = (i << 6) + j;
        const float dT = dTp[off];
        const float dL = dLp[off];
        const float uu = up[off];
        const float bm = bmp[off];
        const float cm = cmp[off];

        const float aT = __expf(dT * AT);
        const float aL = __expf(dL * AL);

        float bb = fmaf(aT, h, (dT + dL) * bm * uu);
        float aa = aL;

        #pragma unroll
        for (int k = 1; k < 64; k <<= 1) {
            float ua = __shfl_up(aa, (unsigned)k, 64);
            float ub = __shfl_up(bb, (unsigned)k, 64);
            bool valid = (j >= k);
            bb = fmaf(aa, valid ? ub : 0.f, bb);   // b uses OLD a
            aa *= valid ? ua : 1.f;
        }
        h = bb;

        contrib[n][j] = h * cm;
        __syncthreads();
        if (n == 0) {
            float s = 0.f;
            #pragma unroll
            for (int nn = 0; nn < NN; ++nn) s += contrib[nn][j];
            ysp[off] = gelu_exact(s + uu * De);
        }
        __syncthreads();
    }
}

// ---------------------------------------------------------------------------
// K3: out projection. Block per row (b,i): out[b,i,j,:] = ys[b,:,i,j]@ow^T + ob
// ---------------------------------------------------------------------------
__global__ __launch_bounds__(256) void k3_outproj(
    const float* __restrict__ ys_t,
    const float* __restrict__ ow, const float* __restrict__ ob,
    float* __restrict__ out)
{
    __shared__ float ysL[64][65];
    __shared__ float outL[128][65];

    const int row = blockIdx.x;
    const int b = row >> 6, i = row & 63;
    const int t = threadIdx.x;
    const int w = t >> 6, j = t & 63;

    float acc[32];
    #pragma unroll
    for (int dd = 0; dd < 32; ++dd) acc[dd] = 0.f;

    for (int ch = 0; ch < 4; ++ch) {
        for (int idx = t; idx < 64 * 64; idx += 256) {
            const int ee = idx >> 6, jj = idx & 63;
            ysL[ee][jj] = ys_t[(((size_t)(b * EE + ch * 64 + ee) * HH + i) << 6) + jj];
        }
        __syncthreads();
        for (int ee = 0; ee < 64; ++ee) {
            const float yv = ysL[ee][j];
            const int e = ch * 64 + ee;
            #pragma unroll
            for (int dd = 0; dd < 32; ++dd)
                acc[dd] = fmaf(ow[(w * 32 + dd) * EE + e], yv, acc[dd]);
        }
        __syncthreads();
    }

    #pragma unroll
    for (int dd = 0; dd < 32; ++dd) outL[w * 32 + dd][j] = acc[dd] + ob[w * 32 + dd];
    __syncthreads();

    float* orow = out + (size_t)row * (WW * DM);
    for (int idx = t; idx < WW * DM; idx += 256) {
        orow[idx] = outL[idx & 127][idx >> 7];
    }
}

extern "C" void kernel_launch(void* const* d_in, const int* in_sizes, int n_in,
                              void* d_out, int out_size, void* d_ws, size_t ws_size,
                              hipStream_t stream) {
    const float* x    = (const float*)d_in[0];
    const float* ipw  = (const float*)d_in[1];
    const float* ipb  = (const float*)d_in[2];
    const float* xpw  = (const float*)d_in[3];
    const float* xpb  = (const float*)d_in[4];
    const float* dtTw = (const float*)d_in[5];
    const float* dtTb = (const float*)d_in[6];
    const float* dtLw = (const float*)d_in[7];
    const float* dtLb = (const float*)d_in[8];
    const float* ATl  = (const float*)d_in[9];
    const float* ALl  = (const float*)d_in[10];
    const float* Dp   = (const float*)d_in[11];
    const float* ow   = (const float*)d_in[12];
    const float* ob   = (const float*)d_in[13];
    float* out = (float*)d_out;

    // workspace carve-up (floats): 4 x [B,E,H,W] (2,097,152 each) + 2 x [B,N,H,W]
    float* ws   = (float*)d_ws;
    float* u_t  = ws;
    float* dT_t = u_t  + (size_t)BB * EE * HW;
    float* dL_t = dT_t + (size_t)BB * EE * HW;
    float* ys_t = dL_t + (size_t)BB * EE * HW;
    float* Bm_t = ys_t + (size_t)BB * EE * HW;
    float* Cm_t = Bm_t + (size_t)BB * NN * HW;

    k1_proj<<<BB * HH, 256, 0, stream>>>(x, ipw, ipb, xpw, xpb, dtTw, dtTb,
                                         dtLw, dtLb, u_t, dT_t, dL_t, Bm_t, Cm_t);
    k2_scan<<<BB * EE, 1024, 0, stream>>>(u_t, dT_t, dL_t, Bm_t, Cm_t,
                                          ATl, ALl, Dp, ys_t);
    k3_outproj<<<BB * HH, 256, 0, stream>>>(ys_t, ow, ob, out);
}

// Round 2
// 267.500 us; speedup vs baseline: 1.5942x; 1.5942x over previous
//
#include <hip/hip_runtime.h>
#include <math.h>

// Problem constants
#define BB 2
#define HH 64
#define WW 64
#define DM 128
#define EE 256
#define NN 16
#define RR 8
#define HW (HH*WW)          // 4096

__device__ __forceinline__ float gelu_exact(float v) {
    return 0.5f * v * (1.f + erff(v * 0.70710678118654752440f));
}
__device__ __forceinline__ float softplus_f(float v) {
    return fmaxf(v, 0.f) + log1pf(__expf(-fabsf(v)));
}

// ---------------------------------------------------------------------------
// K1a: u = gelu(x@ipw^T + ipb) written transposed u_t[B,E,H,W].
// grid = (B*H rows) * 8 e-chunks of 32. block 256 thr: lane j = column,
// wave w -> e = ec*32 + w*8 + (0..7). K=128 from LDS-staged x row.
// ---------------------------------------------------------------------------
__global__ __launch_bounds__(256) void k1a_u(
    const float* __restrict__ x,
    const float* __restrict__ ipw, const float* __restrict__ ipb,
    float* __restrict__ u_t)
{
    __shared__ float xs[64][129];

    const int blk = blockIdx.x;
    const int row = blk >> 3;            // b*64 + i
    const int ec  = blk & 7;
    const int b = row >> 6, i = row & 63;
    const int t = threadIdx.x;
    const int w = t >> 6, j = t & 63;

    const float* xrow = x + (size_t)row * (WW * DM);
    for (int idx = t; idx < WW * DM; idx += 256)
        xs[idx >> 7][idx & 127] = xrow[idx];
    __syncthreads();

    const int e0 = ec * 32 + w * 8;
    float acc[8];
    #pragma unroll
    for (int ee = 0; ee < 8; ++ee) acc[ee] = 0.f;

    for (int k = 0; k < DM; ++k) {
        const float xv = xs[j][k];
        #pragma unroll
        for (int ee = 0; ee < 8; ++ee)
            acc[ee] = fmaf(xv, ipw[(e0 + ee) * DM + k], acc[ee]);
    }
    #pragma unroll
    for (int ee = 0; ee < 8; ++ee) {
        const int e = e0 + ee;
        u_t[(((size_t)(b * EE + e) * HH + i) << 6) + j] = gelu_exact(acc[ee] + ipb[e]);
    }
}

// ---------------------------------------------------------------------------
// K1b: dbc = u@xpw^T + xpb; deltaT/L = softplus(d@dtw^T + b); Bm/Cm split.
// Block per row (b,i), 256 thr. u staged from u_t (coalesced per-e rows).
// ---------------------------------------------------------------------------
__global__ __launch_bounds__(256) void k1b_proj(
    const float* __restrict__ u_t,
    const float* __restrict__ xpw, const float* __restrict__ xpb,
    const float* __restrict__ dtTw, const float* __restrict__ dtTb,
    const float* __restrict__ dtLw, const float* __restrict__ dtLb,
    float* __restrict__ dT_t, float* __restrict__ dL_t,
    float* __restrict__ Bm_t, float* __restrict__ Cm_t)
{
    __shared__ float us[256][65];
    __shared__ float dbcs[48][65];

    const int row = blockIdx.x;
    const int b = row >> 6, i = row & 63;
    const int t = threadIdx.x;
    const int w = t >> 6, j = t & 63;

    for (int idx = t; idx < EE * 64; idx += 256) {
        const int e = idx >> 6, jj = idx & 63;
        us[e][jj] = u_t[(((size_t)(b * EE + e) * HH + i) << 6) + jj];
    }
    __syncthreads();

    float accD[12];
    #pragma unroll
    for (int cc = 0; cc < 12; ++cc) accD[cc] = 0.f;
    for (int e = 0; e < EE; ++e) {
        const float uv = us[e][j];
        #pragma unroll
        for (int cc = 0; cc < 12; ++cc)
            accD[cc] = fmaf(xpw[(w * 12 + cc) * EE + e], uv, accD[cc]);
    }
    #pragma unroll
    for (int cc = 0; cc < 12; ++cc)
        dbcs[w * 12 + cc][j] = accD[cc] + xpb[w * 12 + cc];
    __syncthreads();

    for (int n = w; n < NN; n += 4) {
        Bm_t[(((size_t)(b * NN + n) * HH + i) << 6) + j] = dbcs[2 * RR + n][j];
        Cm_t[(((size_t)(b * NN + n) * HH + i) << 6) + j] = dbcs[2 * RR + NN + n][j];
    }

    float dtv[8], dlv[8];
    #pragma unroll
    for (int r = 0; r < 8; ++r) { dtv[r] = dbcs[r][j]; dlv[r] = dbcs[RR + r][j]; }
    for (int ee = 0; ee < 64; ++ee) {
        const int e = w * 64 + ee;
        float sT = dtTb[e], sL = dtLb[e];
        #pragma unroll
        for (int r = 0; r < 8; ++r) {
            sT = fmaf(dtv[r], dtTw[e * RR + r], sT);
            sL = fmaf(dlv[r], dtLw[e * RR + r], sL);
        }
        dT_t[(((size_t)(b * EE + e) * HH + i) << 6) + j] = softplus_f(sT);
        dL_t[(((size_t)(b * EE + e) * HH + i) << 6) + j] = softplus_f(sL);
    }
}

// ---------------------------------------------------------------------------
// K2: wavefront scan (UNCHANGED this round). Block per (b,e): 16 waves,
// wave n handles state n, lane j = column. Hillis-Steele over W per row.
// ---------------------------------------------------------------------------
__global__ __launch_bounds__(1024) void k2_scan(
    const float* __restrict__ u_t, const float* __restrict__ dT_t,
    const float* __restrict__ dL_t, const float* __restrict__ Bm_t,
    const float* __restrict__ Cm_t, const float* __restrict__ ATl,
    const float* __restrict__ ALl, const float* __restrict__ Dp,
    float* __restrict__ ys_t)
{
    __shared__ float contrib[NN][65];

    const int be = blockIdx.x;
    const int b = be >> 8, e = be & 255;
    const int t = threadIdx.x;
    const int n = t >> 6, j = t & 63;

    const float AT = -__expf(ATl[e * NN + n]);
    const float AL = -__expf(ALl[e * NN + n]);
    const float De = Dp[e];

    const float* dTp = dT_t + ((size_t)be << 12);
    const float* dLp = dL_t + ((size_t)be << 12);
    const float* up  = u_t  + ((size_t)be << 12);
    const float* bmp = Bm_t + ((size_t)(b * NN + n) << 12);
    const float* cmp = Cm_t + ((size_t)(b * NN + n) << 12);
    float* ysp = ys_t + ((size_t)be << 12);

    float h = 0.f;
    for (int i = 0; i < HH; ++i) {
        const int off = (i << 6) + j;
        const float dT = dTp[off];
        const float dL = dLp[off];
        const float uu = up[off];
        const float bm = bmp[off];
        const float cm = cmp[off];

        const float aT = __expf(dT * AT);
        const float aL = __expf(dL * AL);

        float bb = fmaf(aT, h, (dT + dL) * bm * uu);
        float aa = aL;

        #pragma unroll
        for (int k = 1; k < 64; k <<= 1) {
            float ua = __shfl_up(aa, (unsigned)k, 64);
            float ub = __shfl_up(bb, (unsigned)k, 64);
            bool valid = (j >= k);
            bb = fmaf(aa, valid ? ub : 0.f, bb);
            aa *= valid ? ua : 1.f;
        }
        h = bb;

        contrib[n][j] = h * cm;
        __syncthreads();
        if (n == 0) {
            float s = 0.f;
            #pragma unroll
            for (int nn = 0; nn < NN; ++nn) s += contrib[nn][j];
            ysp[off] = gelu_exact(s + uu * De);
        }
        __syncthreads();
    }
}

// ---------------------------------------------------------------------------
// K3: out projection, re-tiled. grid = (B*H rows) * 4 d-chunks of 32.
// Wave w -> d = dc*32 + w*8 + (0..7); K=256 via 4 LDS-staged e-chunks.
// ---------------------------------------------------------------------------
__global__ __launch_bounds__(256) void k3_outproj(
    const float* __restrict__ ys_t,
    const float* __restrict__ ow, const float* __restrict__ ob,
    float* __restrict__ out)
{
    __shared__ float ysL[64][65];

    const int blk = blockIdx.x;
    const int row = blk >> 2;
    const int dc  = blk & 3;
    const int b = row >> 6, i = row & 63;
    const int t = threadIdx.x;
    const int w = t >> 6, j = t & 63;
    const int d0 = dc * 32 + w * 8;

    float acc[8];
    #pragma unroll
    for (int dd = 0; dd < 8; ++dd) acc[dd] = 0.f;

    for (int ch = 0; ch < 4; ++ch) {
        __syncthreads();
        for (int idx = t; idx < 64 * 64; idx += 256) {
            const int ee = idx >> 6, jj = idx & 63;
            ysL[ee][jj] = ys_t[(((size_t)(b * EE + ch * 64 + ee) * HH + i) << 6) + jj];
        }
        __syncthreads();
        for (int e64 = 0; e64 < 64; ++e64) {
            const float yv = ysL[e64][j];
            const int e = ch * 64 + e64;
            #pragma unroll
            for (int dd = 0; dd < 8; ++dd)
                acc[dd] = fmaf(ow[(d0 + dd) * EE + e], yv, acc[dd]);
        }
    }

    float* orow = out + (size_t)row * (WW * DM) + (size_t)j * DM + d0;
    #pragma unroll
    for (int dd = 0; dd < 8; ++dd) orow[dd] = acc[dd] + ob[d0 + dd];
}

extern "C" void kernel_launch(void* const* d_in, const int* in_sizes, int n_in,
                              void* d_out, int out_size, void* d_ws, size_t ws_size,
                              hipStream_t stream) {
    const float* x    = (const float*)d_in[0];
    const float* ipw  = (const float*)d_in[1];
    const float* ipb  = (const float*)d_in[2];
    const float* xpw  = (const float*)d_in[3];
    const float* xpb  = (const float*)d_in[4];
    const float* dtTw = (const float*)d_in[5];
    const float* dtTb = (const float*)d_in[6];
    const float* dtLw = (const float*)d_in[7];
    const float* dtLb = (const float*)d_in[8];
    const float* ATl  = (const float*)d_in[9];
    const float* ALl  = (const float*)d_in[10];
    const float* Dp   = (const float*)d_in[11];
    const float* ow   = (const float*)d_in[12];
    const float* ob   = (const float*)d_in[13];
    float* out = (float*)d_out;

    float* ws   = (float*)d_ws;
    float* u_t  = ws;
    float* dT_t = u_t  + (size_t)BB * EE * HW;
    float* dL_t = dT_t + (size_t)BB * EE * HW;
    float* ys_t = dL_t + (size_t)BB * EE * HW;
    float* Bm_t = ys_t + (size_t)BB * EE * HW;
    float* Cm_t = Bm_t + (size_t)BB * NN * HW;

    k1a_u<<<BB * HH * 8, 256, 0, stream>>>(x, ipw, ipb, u_t);
    k1b_proj<<<BB * HH, 256, 0, stream>>>(u_t, xpw, xpb, dtTw, dtTb, dtLw, dtLb,
                                          dT_t, dL_t, Bm_t, Cm_t);
    k2_scan<<<BB * EE, 1024, 0, stream>>>(u_t, dT_t, dL_t, Bm_t, Cm_t,
                                          ATl, ALl, Dp, ys_t);
    k3_outproj<<<BB * HH * 4, 256, 0, stream>>>(ys_t, ow, ob, out);
}

// Round 3
// 176.380 us; speedup vs baseline: 2.4179x; 1.5166x over previous
//
#include <hip/hip_runtime.h>
#include <math.h>

// Problem constants
#define BB 2
#define HH 64
#define WW 64
#define DM 128
#define EE 256
#define NN 16
#define RR 8
#define HW (HH*WW)          // 4096

__device__ __forceinline__ float gelu_exact(float v) {
    return 0.5f * v * (1.f + erff(v * 0.70710678118654752440f));
}
__device__ __forceinline__ float softplus_f(float v) {
    return fmaxf(v, 0.f) + log1pf(__expf(-fabsf(v)));
}

// ---------------------------------------------------------------------------
// K1a: u = gelu(x@ipw^T + ipb) written transposed u_t[B,E,H,W].
// grid = (B*H rows) * 8 e-chunks of 32. block 256 thr.
// ---------------------------------------------------------------------------
__global__ __launch_bounds__(256) void k1a_u(
    const float* __restrict__ x,
    const float* __restrict__ ipw, const float* __restrict__ ipb,
    float* __restrict__ u_t)
{
    __shared__ float xs[64][129];

    const int blk = blockIdx.x;
    const int row = blk >> 3;            // b*64 + i
    const int ec  = blk & 7;
    const int b = row >> 6, i = row & 63;
    const int t = threadIdx.x;
    const int w = t >> 6, j = t & 63;

    const float* xrow = x + (size_t)row * (WW * DM);
    for (int idx = t; idx < WW * DM; idx += 256)
        xs[idx >> 7][idx & 127] = xrow[idx];
    __syncthreads();

    const int e0 = ec * 32 + w * 8;
    float acc[8];
    #pragma unroll
    for (int ee = 0; ee < 8; ++ee) acc[ee] = 0.f;

    for (int k = 0; k < DM; ++k) {
        const float xv = xs[j][k];
        #pragma unroll
        for (int ee = 0; ee < 8; ++ee)
            acc[ee] = fmaf(xv, ipw[(e0 + ee) * DM + k], acc[ee]);
    }
    #pragma unroll
    for (int ee = 0; ee < 8; ++ee) {
        const int e = e0 + ee;
        u_t[(((size_t)(b * EE + e) * HH + i) << 6) + j] = gelu_exact(acc[ee] + ipb[e]);
    }
}

// ---------------------------------------------------------------------------
// K1b: dbc = u@xpw^T + xpb; deltaT/L = softplus(d@dtw^T + b); Bm/Cm split.
// Block per (b,i,j-quarter): 512 blocks, 256 thr. u staged transposed in LDS,
// xpw staged in LDS (both padded to 260 for float4 LDS reads, <=2-way banks).
// ---------------------------------------------------------------------------
__global__ __launch_bounds__(256) void k1b_proj(
    const float* __restrict__ u_t,
    const float* __restrict__ xpw, const float* __restrict__ xpb,
    const float* __restrict__ dtTw, const float* __restrict__ dtTb,
    const float* __restrict__ dtLw, const float* __restrict__ dtLb,
    float* __restrict__ dT_t, float* __restrict__ dL_t,
    float* __restrict__ Bm_t, float* __restrict__ Cm_t)
{
    __shared__ float usT[16][260];     // [jj][e]
    __shared__ float xpwL[48][260];    // [c][e]
    __shared__ float dbcs[48][17];

    const int blk = blockIdx.x;        // (b*64+i)*4 + jq
    const int jq = blk & 3;
    const int row = blk >> 2;
    const int b = row >> 6, i = row & 63;
    const int j0 = jq * 16;
    const int t = threadIdx.x;

    // stage xpw (48x256) coalesced float4
    for (int idx = t; idx < 48 * 64; idx += 256) {
        const int c = idx >> 6, e4 = idx & 63;
        const float4 v = ((const float4*)xpw)[(size_t)c * 64 + e4];
        *(float4*)&xpwL[c][4 * e4] = v;
    }
    // stage u transposed: usT[jj][e]
    {
        const int jj = t & 15, eg = t >> 4;
        #pragma unroll
        for (int r = 0; r < 16; ++r) {
            const int e = eg * 16 + r;
            usT[jj][e] = u_t[(((size_t)(b * EE + e) * HH + i) << 6) + j0 + jj];
        }
    }
    __syncthreads();

    // GEMM: thread (jj, cg): outputs c = 3*cg + {0,1,2}, K=256 via float4
    {
        const int jj = t & 15, cg = t >> 4;
        float a0 = 0.f, a1 = 0.f, a2 = 0.f;
        for (int e4 = 0; e4 < 64; ++e4) {
            const float4 uv = *(const float4*)&usT[jj][4 * e4];
            const float4 w0 = *(const float4*)&xpwL[3 * cg + 0][4 * e4];
            const float4 w1 = *(const float4*)&xpwL[3 * cg + 1][4 * e4];
            const float4 w2 = *(const float4*)&xpwL[3 * cg + 2][4 * e4];
            a0 = fmaf(uv.x, w0.x, a0); a0 = fmaf(uv.y, w0.y, a0);
            a0 = fmaf(uv.z, w0.z, a0); a0 = fmaf(uv.w, w0.w, a0);
            a1 = fmaf(uv.x, w1.x, a1); a1 = fmaf(uv.y, w1.y, a1);
            a1 = fmaf(uv.z, w1.z, a1); a1 = fmaf(uv.w, w1.w, a1);
            a2 = fmaf(uv.x, w2.x, a2); a2 = fmaf(uv.y, w2.y, a2);
            a2 = fmaf(uv.z, w2.z, a2); a2 = fmaf(uv.w, w2.w, a2);
        }
        dbcs[3 * cg + 0][jj] = a0 + xpb[3 * cg + 0];
        dbcs[3 * cg + 1][jj] = a1 + xpb[3 * cg + 1];
        dbcs[3 * cg + 2][jj] = a2 + xpb[3 * cg + 2];
    }
    __syncthreads();

    // Bm / Cm
    {
        const int n = t >> 4, jj = t & 15;
        Bm_t[(((size_t)(b * NN + n) * HH + i) << 6) + j0 + jj] = dbcs[2 * RR + n][jj];
        Cm_t[(((size_t)(b * NN + n) * HH + i) << 6) + j0 + jj] = dbcs[2 * RR + NN + n][jj];
    }

    // deltas: thread (eg, jj) handles e = eg*16 .. eg*16+15
    {
        const int jj = t & 15, eg = t >> 4;
        float dtv[8], dlv[8];
        #pragma unroll
        for (int r = 0; r < 8; ++r) { dtv[r] = dbcs[r][jj]; dlv[r] = dbcs[RR + r][jj]; }
        #pragma unroll 4
        for (int ee = 0; ee < 16; ++ee) {
            const int e = eg * 16 + ee;
            float sT = dtTb[e], sL = dtLb[e];
            #pragma unroll
            for (int r = 0; r < 8; ++r) {
                sT = fmaf(dtv[r], dtTw[e * RR + r], sT);
                sL = fmaf(dlv[r], dtLw[e * RR + r], sL);
            }
            dT_t[(((size_t)(b * EE + e) * HH + i) << 6) + j0 + jj] = softplus_f(sT);
            dL_t[(((size_t)(b * EE + e) * HH + i) << 6) + j0 + jj] = softplus_f(sL);
        }
    }
}

// ---------------------------------------------------------------------------
// K2: wavefront scan, segmented. Block per (b,e): 256 thr = 4 waves.
// Wave w: 4 channels n = w*4+c (c = lane>>4), 16-lane segments (jj = lane&15),
// each lane owns cols 4*jj..4*jj+3. Per row: local scan of 4 + 4-step masked
// shfl_up over lane aggregates + prefix shift. n-reduce via double-buffered
// LDS, one barrier per row, wave 0 finalizes (sum16 + u*D + gelu + store).
// ---------------------------------------------------------------------------
__global__ __launch_bounds__(256) void k2_scan(
    const float* __restrict__ u_t, const float* __restrict__ dT_t,
    const float* __restrict__ dL_t, const float* __restrict__ Bm_t,
    const float* __restrict__ Cm_t, const float* __restrict__ ATl,
    const float* __restrict__ ALl, const float* __restrict__ Dp,
    float* __restrict__ ys_t)
{
    __shared__ float red[2][NN][65];

    const int be = blockIdx.x;           // b*256 + e
    const int b = be >> 8, e = be & 255;
    const int t = threadIdx.x;
    const int w = t >> 6, lane = t & 63;
    const int c = lane >> 4, jj = lane & 15;
    const int n = w * 4 + c;

    const float LOG2E = 1.44269504088896340736f;
    const float AT2 = -__expf(ATl[e * NN + n]) * LOG2E;
    const float AL2 = -__expf(ALl[e * NN + n]) * LOG2E;
    const float De = Dp[e];

    const float* dTp = dT_t + ((size_t)be << 12) + 4 * jj;
    const float* dLp = dL_t + ((size_t)be << 12) + 4 * jj;
    const float* up  = u_t  + ((size_t)be << 12) + 4 * jj;
    const float* bmp = Bm_t + ((size_t)(b * NN + n) << 12) + 4 * jj;
    const float* cmp = Cm_t + ((size_t)(b * NN + n) << 12) + 4 * jj;
    const float* upR = u_t + ((size_t)be << 12);   // wave0 full-row access
    float* ysp = ys_t + ((size_t)be << 12);

    float hprev[4];
    #pragma unroll
    for (int k = 0; k < 4; ++k) hprev[k] = 0.f;

    // prefetch row 0
    float4 dT4 = *(const float4*)(dTp);
    float4 dL4 = *(const float4*)(dLp);
    float4 u4  = *(const float4*)(up);
    float4 bm4 = *(const float4*)(bmp);
    float4 cm4 = *(const float4*)(cmp);

    for (int i = 0; i < HH; ++i) {
        // prefetch row i+1 (clamped) - independent of h chain
        const int ip = (i < HH - 1) ? (i + 1) : i;
        const float4 dT4n = *(const float4*)(dTp + (ip << 6));
        const float4 dL4n = *(const float4*)(dLp + (ip << 6));
        const float4 u4n  = *(const float4*)(up  + (ip << 6));
        const float4 bm4n = *(const float4*)(bmp + (ip << 6));
        const float4 cm4n = *(const float4*)(cmp + (ip << 6));

        const float dT[4] = {dT4.x, dT4.y, dT4.z, dT4.w};
        const float dL[4] = {dL4.x, dL4.y, dL4.z, dL4.w};
        const float uu[4] = {u4.x, u4.y, u4.z, u4.w};
        const float bm[4] = {bm4.x, bm4.y, bm4.z, bm4.w};
        const float cm[4] = {cm4.x, cm4.y, cm4.z, cm4.w};

        float aL[4], binp[4];
        #pragma unroll
        for (int k = 0; k < 4; ++k) {
            const float aT = exp2f(dT[k] * AT2);
            aL[k] = exp2f(dL[k] * AL2);
            const float bx = (dT[k] + dL[k]) * bm[k] * uu[k];
            binp[k] = fmaf(aT, hprev[k], bx);
        }
        // local inclusive scan over 4 cols
        float cumA[4], cumB[4];
        cumA[0] = aL[0]; cumB[0] = binp[0];
        #pragma unroll
        for (int k = 1; k < 4; ++k) {
            cumB[k] = fmaf(aL[k], cumB[k - 1], binp[k]);
            cumA[k] = aL[k] * cumA[k - 1];
        }
        // 16-lane segmented Hillis-Steele on aggregates
        float Ag = cumA[3], Bg = cumB[3];
        #pragma unroll
        for (int s = 1; s < 16; s <<= 1) {
            const float uA = __shfl_up(Ag, (unsigned)s, 64);
            const float uB = __shfl_up(Bg, (unsigned)s, 64);
            if (jj >= s) { Bg = fmaf(Ag, uB, Bg); Ag *= uA; }
        }
        // exclusive prefix (b-part only)
        float pB = __shfl_up(Bg, 1u, 64);
        if (jj == 0) pB = 0.f;

        const int buf = i & 1;
        #pragma unroll
        for (int k = 0; k < 4; ++k) {
            const float h = fmaf(cumA[k], pB, cumB[k]);
            hprev[k] = h;
            red[buf][n][4 * jj + k] = h * cm[k];
        }
        __syncthreads();

        if (w == 0) {
            const float uD = upR[(i << 6) + lane];
            float ssum = 0.f;
            #pragma unroll
            for (int nn = 0; nn < NN; ++nn) ssum += red[buf][nn][lane];
            ysp[(i << 6) + lane] = gelu_exact(fmaf(uD, De, ssum));
        }

        dT4 = dT4n; dL4 = dL4n; u4 = u4n; bm4 = bm4n; cm4 = cm4n;
    }
}

// ---------------------------------------------------------------------------
// K3: out projection. grid = (B*H rows) * 4 d-chunks of 32.
// ---------------------------------------------------------------------------
__global__ __launch_bounds__(256) void k3_outproj(
    const float* __restrict__ ys_t,
    const float* __restrict__ ow, const float* __restrict__ ob,
    float* __restrict__ out)
{
    __shared__ float ysL[64][65];

    const int blk = blockIdx.x;
    const int row = blk >> 2;
    const int dc  = blk & 3;
    const int b = row >> 6, i = row & 63;
    const int t = threadIdx.x;
    const int w = t >> 6, j = t & 63;
    const int d0 = dc * 32 + w * 8;

    float acc[8];
    #pragma unroll
    for (int dd = 0; dd < 8; ++dd) acc[dd] = 0.f;

    for (int ch = 0; ch < 4; ++ch) {
        __syncthreads();
        for (int idx = t; idx < 64 * 64; idx += 256) {
            const int ee = idx >> 6, jj = idx & 63;
            ysL[ee][jj] = ys_t[(((size_t)(b * EE + ch * 64 + ee) * HH + i) << 6) + jj];
        }
        __syncthreads();
        for (int e64 = 0; e64 < 64; ++e64) {
            const float yv = ysL[e64][j];
            const int e = ch * 64 + e64;
            #pragma unroll
            for (int dd = 0; dd < 8; ++dd)
                acc[dd] = fmaf(ow[(d0 + dd) * EE + e], yv, acc[dd]);
        }
    }

    float* orow = out + (size_t)row * (WW * DM) + (size_t)j * DM + d0;
    #pragma unroll
    for (int dd = 0; dd < 8; ++dd) orow[dd] = acc[dd] + ob[d0 + dd];
}

extern "C" void kernel_launch(void* const* d_in, const int* in_sizes, int n_in,
                              void* d_out, int out_size, void* d_ws, size_t ws_size,
                              hipStream_t stream) {
    const float* x    = (const float*)d_in[0];
    const float* ipw  = (const float*)d_in[1];
    const float* ipb  = (const float*)d_in[2];
    const float* xpw  = (const float*)d_in[3];
    const float* xpb  = (const float*)d_in[4];
    const float* dtTw = (const float*)d_in[5];
    const float* dtTb = (const float*)d_in[6];
    const float* dtLw = (const float*)d_in[7];
    const float* dtLb = (const float*)d_in[8];
    const float* ATl  = (const float*)d_in[9];
    const float* ALl  = (const float*)d_in[10];
    const float* Dp   = (const float*)d_in[11];
    const float* ow   = (const float*)d_in[12];
    const float* ob   = (const float*)d_in[13];
    float* out = (float*)d_out;

    float* ws   = (float*)d_ws;
    float* u_t  = ws;
    float* dT_t = u_t  + (size_t)BB * EE * HW;
    float* dL_t = dT_t + (size_t)BB * EE * HW;
    float* ys_t = dL_t + (size_t)BB * EE * HW;
    float* Bm_t = ys_t + (size_t)BB * EE * HW;
    float* Cm_t = Bm_t + (size_t)BB * NN * HW;

    k1a_u<<<BB * HH * 8, 256, 0, stream>>>(x, ipw, ipb, u_t);
    k1b_proj<<<BB * HH * 4, 256, 0, stream>>>(u_t, xpw, xpb, dtTw, dtTb, dtLw, dtLb,
                                              dT_t, dL_t, Bm_t, Cm_t);
    k2_scan<<<BB * EE, 256, 0, stream>>>(u_t, dT_t, dL_t, Bm_t, Cm_t,
                                         ATl, ALl, Dp, ys_t);
    k3_outproj<<<BB * HH * 4, 256, 0, stream>>>(ys_t, ow, ob, out);
}